// Round 19
// baseline (121.411 us; speedup 1.0000x reference)
//
#include <hip/hip_runtime.h>
#include <math.h>

#define S1C 10
#define S2C 25
#define DC 128
#define NSAMP 261
#define NBATCH 2048
#define N_NODES 100000
#define FEA_SZ (128*2048)

// ws layout (float slots):
//   [0:128)    a1 = V1h1a^T w1[:128]
//   [128:256)  a2 = V1h1a^T w1[128:]
//   [256:384)  b1 = V1h0a^T w0[:128]
//   [384:512)  b2 = V1h0a^T w0[128:]
//   WS_BPK:  Bpack bf16 (32768 ushorts), MFMA B fragments
//   WS_V0T:  V0t[dd][l] = V1h0[l][dd]  (f32)
//   WS_AGGF: aggF[b][s][128] bf16   [f32 fallback path only]
//   WS_XB:   xb[node][128] bf16     [bf16 path only]
#define WS_BPK   512
#define WS_V0T   (WS_BPK + 16384)
#define WS_AGGF  (WS_V0T + 16384)
#define WS_XB    (WS_AGGF + 1310720)
#define WS_END   (WS_XB + 6400000)

typedef float f32x4 __attribute__((ext_vector_type(4)));
typedef short s16x8 __attribute__((ext_vector_type(8)));
typedef short s16x4 __attribute__((ext_vector_type(4)));

__device__ __forceinline__ float lrelu(float v) { return v > 0.f ? v : 0.01f * v; }
__device__ __forceinline__ float sigm(float v) { return 1.f / (1.f + __expf(-v)); }
__device__ __forceinline__ float dot4(float4 a, float4 b) {
    return a.x * b.x + a.y * b.y + a.z * b.z + a.w * b.w;
}
__device__ __forceinline__ unsigned short f2bf(float f) {
    unsigned u = __float_as_uint(f);
    unsigned r = (u + 0x7FFFu + ((u >> 16) & 1u)) >> 16;
    return (unsigned short)r;
}
__device__ __forceinline__ float bf2f(unsigned short us) {
    return __uint_as_float(((unsigned)us) << 16);
}

// Merged prep: blk 0 -> a1/a2/b1/b2; blks 1..128 -> Bpack; blks 129..192 -> V0t;
// blks >= 193 (bf16 path only) -> x -> xb bf16 conversion (grid-stride).
__global__ void prep_all_kernel(const float* __restrict__ Vh1a, const float* __restrict__ w1,
                                const float* __restrict__ Vh0a, const float* __restrict__ w0,
                                const float* __restrict__ V1h1, const float* __restrict__ Whops,
                                const float* __restrict__ V1h0, const float* __restrict__ x,
                                unsigned short* __restrict__ xb, float* __restrict__ ws) {
    const int blk = blockIdx.x, tid = threadIdx.x;
    if (blk == 0) {
        for (int o = tid; o < 512; o += 256) {
            int which = o >> 7, n = o & 127;
            const float* V = (which < 2) ? Vh1a : Vh0a;
            const float* w = (which < 2) ? w1 : w0;
            int off = (which & 1) * 128;
            float acc = 0.f;
            for (int l = 0; l < 128; ++l) acc += V[l * 128 + n] * w[off + l];
            ws[o] = acc;
        }
    } else if (blk <= 128) {
        int e = (blk - 1) * 256 + tid;          // 0..32767
        int j  = e & 7;
        int l  = (e >> 3) & 63;
        int kb = (e >> 9) & 7;
        int nt = (e >> 12) & 7;
        int d  = nt * 16 + (l & 15);
        int k  = kb * 32 + ((l >> 4) & 3) * 8 + j;
        int which = k >> 7, kk = k & 127;
        float acc = 0.f;
        for (int jj = 0; jj < 128; ++jj)
            acc += Whops[(size_t)d * 256 + which * 128 + jj] * V1h1[(size_t)jj * 128 + kk];
        unsigned short* bpk = (unsigned short*)(ws + WS_BPK);
        bpk[e] = f2bf(acc);
    } else if (blk <= 192) {
        int dd = (blk - 129) * 2 + (tid >> 7);
        int l = tid & 127;
        ws[WS_V0T + (size_t)dd * 128 + l] = V1h0[(size_t)l * 128 + dd];
    } else {
        const int total4 = N_NODES * DC / 4;    // 3,200,000
        const int stride = (gridDim.x - 193) * 256;
        const float4* x4 = (const float4*)x;
        for (int i = (blk - 193) * 256 + tid; i < total4; i += stride) {
            float4 v = x4[i];
            s16x4 o;
            o[0] = (short)f2bf(v.x); o[1] = (short)f2bf(v.y);
            o[2] = (short)f2bf(v.z); o[3] = (short)f2bf(v.w);
            *(s16x4*)(xb + (size_t)i * 4) = o;
        }
    }
}

// ============================ bf16 fused path ============================

// ONE b per block (grid 2048, 4 waves). R14 body (runtime s-loop, single
// register row-buffer -- R15/R17: any two-live-row-set form spills).
// (256,6): kernel's natural allocation is 64 VGPR (measured R18), so an
// 85-VGPR budget still fits spill-free while allowing 24 waves/CU.
__global__ __launch_bounds__(256, 6) void fused_b_kernel(
    const unsigned short* __restrict__ xb, const int* __restrict__ samples,
    const float* __restrict__ ws, float* __restrict__ out)
{
    const int b = blockIdx.x;
    const int tid = threadIdx.x;
    const int wv = tid >> 6, l = tid & 63;
    const int g = l >> 4, seg = l & 15;

    __shared__ __align__(16) short sXb[16][264];   // A tile: t1/t0 | agg/tbar
    __shared__ float sDots[4][32];
    __shared__ float sD1[12];                      // d1[s]=t1.a2; [10]=c0=t0.a1
    __shared__ float sBeta0[10];
    __shared__ float sLgP[4][16];
    __shared__ __align__(16) float sHopH[128];
    __shared__ float sBH[16];

    const int* sidx = samples + (size_t)b * NSAMP;

    // zero pad rows 11..15 (both K halves)
    for (int i = tid; i < 165; i += 256) {
        int rr = i / 33, c8 = i - rr * 33;
        *(s16x8*)(&sXb[11 + rr][c8 * 8]) = (s16x8)(short)0;
    }

    // a1/a2 fragments for this lane's 8-elem column slice
    const float* a1p = ws + seg * 8;
    const float* a2p = ws + 128 + seg * 8;
    float a1r[8], a2r[8];
    #pragma unroll
    for (int e = 0; e < 8; ++e) { a1r[e] = a1p[e]; a2r[e] = a2p[e]; }

    // ---- Phase 1: neighbor pairs (runtime loop => single live row-buffer) ----
    for (int s = wv; s < 10; s += 4) {
        s16x8 v0, v1, v2, v3, v4, v5, v6;
        {
            int r;
            r = 0 * 4 + g; v0 = *(const s16x8*)(xb + (size_t)sidx[11 + s * S2C + r] * DC + seg * 8);
            r = 1 * 4 + g; v1 = *(const s16x8*)(xb + (size_t)sidx[11 + s * S2C + r] * DC + seg * 8);
            r = 2 * 4 + g; v2 = *(const s16x8*)(xb + (size_t)sidx[11 + s * S2C + r] * DC + seg * 8);
            r = 3 * 4 + g; v3 = *(const s16x8*)(xb + (size_t)sidx[11 + s * S2C + r] * DC + seg * 8);
            r = 4 * 4 + g; v4 = *(const s16x8*)(xb + (size_t)sidx[11 + s * S2C + r] * DC + seg * 8);
            r = 5 * 4 + g; v5 = *(const s16x8*)(xb + (size_t)sidx[11 + s * S2C + r] * DC + seg * 8);
            r = 6 * 4 + g;  // 24 (g=0), 25=t1 (g=1), idle (g>=2)
            int node = (r == 24) ? sidx[11 + s * S2C + 24] : ((r == 25) ? sidx[1 + s] : sidx[0]);
            v6 = *(const s16x8*)(xb + (size_t)node * DC + seg * 8);
            if (r > 25) v6 = (s16x8)(short)0;
        }

        // dots: neighbors vs a2; t1 row vs a1 (c1) AND a2 (d1[s])
#define ROWDOT(VV, T)                                                            \
        {                                                                        \
            int r = (T) * 4 + g;                                                 \
            float p = 0.f;                                                       \
            _Pragma("unroll")                                                    \
            for (int e = 0; e < 8; ++e)                                          \
                p += bf2f((unsigned short)(VV)[e]) * ((r == 25) ? a1r[e] : a2r[e]); \
            _Pragma("unroll")                                                    \
            for (int o = 8; o > 0; o >>= 1) p += __shfl_xor(p, o, 16);           \
            if (seg == 0 && r <= 25) sDots[wv][r] = p;                           \
        }
        ROWDOT(v0, 0) ROWDOT(v1, 1) ROWDOT(v2, 2) ROWDOT(v3, 3)
        ROWDOT(v4, 4) ROWDOT(v5, 5) ROWDOT(v6, 6)
#undef ROWDOT
        // t1 . a2 (only g==1 holds the t1 row)
        {
            float q = 0.f;
            #pragma unroll
            for (int e = 0; e < 8; ++e) q += bf2f((unsigned short)v6[e]) * a2r[e];
            #pragma unroll
            for (int o = 8; o > 0; o >>= 1) q += __shfl_xor(q, o, 16);
            if (g == 1 && seg == 0) sD1[s] = q;
        }
        asm volatile("" ::: "memory");

        // softmax over 25 (replicated per 32-lane half)
        const int j = l & 31;
        float bt;
        {
            float c1 = sDots[wv][25];
            float dj = (j < 25) ? sDots[wv][j] : 0.f;
            float val = (j < 25) ? lrelu(c1 + dj) : -3.4e38f;
            float m = val;
            #pragma unroll
            for (int o = 16; o > 0; o >>= 1) m = fmaxf(m, __shfl_xor(m, o, 32));
            float e = (j < 25) ? __expf(val - m) : 0.f;
            float ssum = e;
            #pragma unroll
            for (int o = 16; o > 0; o >>= 1) ssum += __shfl_xor(ssum, o, 32);
            bt = e / ssum;
        }
        if (l < 25) out[FEA_SZ + (size_t)b * 260 + s * 26 + 1 + l] = bt;

        // weighted aggregation
        float acc[8];
        #pragma unroll
        for (int e = 0; e < 8; ++e) acc[e] = 0.f;
#define ROWACC(VV, T)                                                            \
        {                                                                        \
            int r = (T) * 4 + g;                                                 \
            float btr = __shfl(bt, r & 31, 32);                                  \
            _Pragma("unroll")                                                    \
            for (int e = 0; e < 8; ++e) acc[e] += btr * bf2f((unsigned short)(VV)[e]); \
        }
        ROWACC(v0, 0) ROWACC(v1, 1) ROWACC(v2, 2) ROWACC(v3, 3)
        ROWACC(v4, 4) ROWACC(v5, 5) ROWACC(v6, 6)
#undef ROWACC
        #pragma unroll
        for (int e = 0; e < 8; ++e) {
            acc[e] += __shfl_xor(acc[e], 16, 64);
            acc[e] += __shfl_xor(acc[e], 32, 64);
        }
        if (g == 0) {
            s16x8 o8;
            #pragma unroll
            for (int e = 0; e < 8; ++e) o8[e] = (short)f2bf(acc[e]);
            *(s16x8*)(&sXb[s][128 + seg * 8]) = o8;
        }
        if (g == 1) *(s16x8*)(&sXb[s][seg * 8]) = v6;   // t1 row into A tile
    }

    // wave 3: t0 row -> sXb[10][0:128), c0 = t0.a1 -> sD1[10]
    if (wv == 3 && g == 0) {
        s16x8 v = *(const s16x8*)(xb + (size_t)sidx[0] * DC + seg * 8);
        *(s16x8*)(&sXb[10][seg * 8]) = v;
        float p = 0.f;
        #pragma unroll
        for (int e = 0; e < 8; ++e) p += bf2f((unsigned short)v[e]) * a1r[e];
        #pragma unroll
        for (int o = 8; o > 0; o >>= 1) p += __shfl_xor(p, o, 16);
        if (seg == 0) sD1[10] = p;
    }
    __syncthreads();

    // ---- beta0 ----
    if (tid < 16) {
        float cc = sD1[10];
        float v = (tid < 10) ? lrelu(cc + sD1[tid]) : -3.4e38f;
        float m = v;
        for (int o = 8; o > 0; o >>= 1) m = fmaxf(m, __shfl_xor(m, o, 16));
        float e = (tid < 10) ? __expf(v - m) : 0.f;
        float ss = e;
        for (int o = 8; o > 0; o >>= 1) ss += __shfl_xor(ss, o, 16);
        if (tid < 10) sBeta0[tid] = e / ss;
    }
    __syncthreads();

    // tbar -> agg half of row 10
    if (tid < 128) {
        float acc = 0.f;
        #pragma unroll
        for (int s = 0; s < 10; ++s)
            acc += sBeta0[s] * bf2f((unsigned short)sXb[s][tid]);
        sXb[10][128 + tid] = (short)f2bf(acc);
    }
    __syncthreads();

    // ---- MFMA GEMM: wave wv covers n-tiles {2wv, 2wv+1}, 8 k-blocks ----
    const unsigned short* bpk = (const unsigned short*)(ws + WS_BPK);
    const int lane = l;
    const int lg16 = l >> 4, l15 = l & 15;
    const int nt0 = 2 * wv, nt1 = nt0 + 1;
    f32x4 acc0 = {0.f, 0.f, 0.f, 0.f}, acc1 = {0.f, 0.f, 0.f, 0.f};
    #pragma unroll
    for (int kb = 0; kb < 8; ++kb) {
        s16x8 a0 = *(const s16x8*)(&sXb[l15][kb * 32 + lg16 * 8]);
        s16x8 bw0 = *(const s16x8*)(bpk + ((size_t)(nt0 * 8 + kb) * 64 + lane) * 8);
        s16x8 bw1 = *(const s16x8*)(bpk + ((size_t)(nt1 * 8 + kb) * 64 + lane) * 8);
        acc0 = __builtin_amdgcn_mfma_f32_16x16x32_bf16(a0, bw0, acc0, 0, 0, 0);
        acc1 = __builtin_amdgcn_mfma_f32_16x16x32_bf16(a0, bw1, acc1, 0, 0, 0);
    }

    float h0[4], h1[4];
    #pragma unroll
    for (int r = 0; r < 4; ++r) { h0[r] = sigm(acc0[r]); h1[r] = sigm(acc1[r]); }

    // logit partials over this wave's 32 cols
    const int c0 = nt0 * 16 + l15, c1 = nt1 * 16 + l15;
    const float b1c0 = ws[256 + c0], b1c1 = ws[256 + c1];
    const float b2c0 = ws[384 + c0], b2c1 = ws[384 + c1];
    #pragma unroll
    for (int r = 0; r < 4; ++r) {
        int s = lg16 * 4 + r;
        float p;
        if (s < 10)       p = h0[r] * b2c0 + h1[r] * b2c1;
        else if (s == 10) p = h0[r] * b1c0 + h1[r] * b1c1;
        else              p = 0.f;
        #pragma unroll
        for (int o = 1; o < 16; o <<= 1) p += __shfl_xor(p, o, 64);
        if (l15 == 0) sLgP[wv][s] = p;
    }
    __syncthreads();

    // beta_h
    if (tid < 16) {
        float lgj = 0.f, lg10 = 0.f;
        #pragma unroll
        for (int w2 = 0; w2 < 4; ++w2) {
            lgj  += sLgP[w2][tid];
            lg10 += sLgP[w2][10];
        }
        float v = (tid < 10) ? lrelu(lg10 + lgj) : -3.4e38f;
        float m = v;
        for (int o = 8; o > 0; o >>= 1) m = fmaxf(m, __shfl_xor(m, o, 16));
        float e = (tid < 10) ? __expf(v - m) : 0.f;
        float ss = e;
        for (int o = 8; o > 0; o >>= 1) ss += __shfl_xor(ss, o, 16);
        float bh = (tid < 10) ? e / ss : 0.f;
        sBH[tid] = bh;
        if (tid < 10) out[FEA_SZ + (size_t)b * 260 + tid * 26] = bh;
    }
    __syncthreads();

    // hopH[c] = sum_s bh[s] h[s][c]
    {
        float p0 = 0.f, p1 = 0.f;
        #pragma unroll
        for (int r = 0; r < 4; ++r) {
            int s = lg16 * 4 + r;
            float bh = sBH[s];
            p0 += bh * h0[r];
            p1 += bh * h1[r];
        }
        p0 += __shfl_xor(p0, 16, 64); p0 += __shfl_xor(p0, 32, 64);
        p1 += __shfl_xor(p1, 16, 64); p1 += __shfl_xor(p1, 32, 64);
        if (lg16 == 0) {
            sHopH[c0] = p0;
            sHopH[c1] = p1;
        }
    }
    __syncthreads();

    // projection: fea_out[c] = sum_dd hopH[dd] V0t[dd][c]; out is fea_out^T
    if (tid < 128) {
        const float* v0t = ws + WS_V0T;
        float acc2 = 0.f;
        for (int dd = 0; dd < 128; dd += 4) {
            float4 hh = *(const float4*)(&sHopH[dd]);
            acc2 += hh.x * v0t[(size_t)(dd + 0) * 128 + tid]
                  + hh.y * v0t[(size_t)(dd + 1) * 128 + tid]
                  + hh.z * v0t[(size_t)(dd + 2) * 128 + tid]
                  + hh.w * v0t[(size_t)(dd + 3) * 128 + tid];
        }
        out[(size_t)tid * 2048 + b] = acc2;
    }
}

// ============================ f32 fallback path (R8, proven) ============================

__global__ __launch_bounds__(256) void nbr_kernel(
    const float* __restrict__ x, const int* __restrict__ samples,
    const float* __restrict__ ws, unsigned short* __restrict__ aggF,
    float* __restrict__ out)
{
    const int s = blockIdx.x, b = blockIdx.y;
    const int tid = threadIdx.x, g = tid >> 5, lane = tid & 31;

    __shared__ __align__(16) float sNbr[25][132];
    __shared__ float sD[26];
    __shared__ float sBeta[25];

    float4 a1v = *(const float4*)(ws + lane * 4);
    float4 a2v = *(const float4*)(ws + 128 + lane * 4);
    const int* sidx = samples + (size_t)b * NSAMP;

    const bool has3 = (g < 2);
    int n0 = sidx[11 + s * S2C + g];
    int n1 = sidx[11 + s * S2C + 8 + g];
    int n2 = sidx[11 + s * S2C + 16 + g];
    int n3 = has3 ? ((g == 0) ? sidx[11 + s * S2C + 24] : sidx[1 + s]) : 0;

    float4 v0 = *(const float4*)(x + (size_t)n0 * DC + lane * 4);
    float4 v1 = *(const float4*)(x + (size_t)n1 * DC + lane * 4);
    float4 v2 = *(const float4*)(x + (size_t)n2 * DC + lane * 4);
    float4 v3 = make_float4(0.f, 0.f, 0.f, 0.f);
    if (has3) v3 = *(const float4*)(x + (size_t)n3 * DC + lane * 4);

    *(float4*)(&sNbr[g][lane * 4]) = v0;
    *(float4*)(&sNbr[8 + g][lane * 4]) = v1;
    *(float4*)(&sNbr[16 + g][lane * 4]) = v2;
    if (g == 0) *(float4*)(&sNbr[24][lane * 4]) = v3;

    float p0 = dot4(v0, a2v);
    float p1 = dot4(v1, a2v);
    float p2 = dot4(v2, a2v);
    float p3 = has3 ? dot4(v3, (g == 0) ? a2v : a1v) : 0.f;
    #pragma unroll
    for (int o = 16; o > 0; o >>= 1) {
        p0 += __shfl_xor(p0, o, 32);
        p1 += __shfl_xor(p1, o, 32);
        p2 += __shfl_xor(p2, o, 32);
        p3 += __shfl_xor(p3, o, 32);
    }
    if (lane == 0) {
        sD[g] = p0; sD[8 + g] = p1; sD[16 + g] = p2;
        if (has3) sD[24 + g] = p3;
    }
    __syncthreads();

    if (tid < 32) {
        float c1 = sD[25];
        float v = (lane < 25) ? lrelu(c1 + sD[lane]) : -3.4e38f;
        float m = v;
        for (int o = 16; o > 0; o >>= 1) m = fmaxf(m, __shfl_xor(m, o, 32));
        float e = (lane < 25) ? __expf(v - m) : 0.f;
        float ssum = e;
        for (int o = 16; o > 0; o >>= 1) ssum += __shfl_xor(ssum, o, 32);
        if (lane < 25) {
            float bt = e / ssum;
            sBeta[lane] = bt;
            out[FEA_SZ + (size_t)b * 260 + s * 26 + 1 + lane] = bt;
        }
    }
    __syncthreads();

    if (tid < 128) {
        float acc = 0.f;
        #pragma unroll
        for (int t = 0; t < 25; ++t) acc += sBeta[t] * sNbr[t][tid];
        aggF[((size_t)b * 10 + s) * 128 + tid] = f2bf(acc);
    }
}

__global__ __launch_bounds__(256, 4) void hopfused_kernel(
    const float* __restrict__ x, const int* __restrict__ samples,
    const float* __restrict__ ws, const unsigned short* __restrict__ aggF,
    float* __restrict__ out)
{
    const int b0 = blockIdx.x * 2;
    const int tid = threadIdx.x;
    const int w = tid >> 6;
    const int lane = tid & 63;
    const int lg16 = lane >> 4;
    const int l15 = lane & 15;

    __shared__ __align__(16) float sX[22][128];
    __shared__ __align__(16) short sXb[32][264];
    __shared__ float sLgP[4][32];
    __shared__ __align__(16) float sHopH[2][128];
    __shared__ float sD[22];
    __shared__ float sBeta0[2][10];
    __shared__ float sBH[2][10];
    __shared__ int sNode[22];

    if (tid < 22) {
        int bb = tid / 11, s = tid - bb * 11;
        sNode[tid] = (s < 10) ? samples[(size_t)(b0 + bb) * NSAMP + 1 + s]
                              : samples[(size_t)(b0 + bb) * NSAMP];
    }
    for (int i = tid; i < 330; i += 256) {
        int rr = i / 33, c8 = i - rr * 33;
        int row = (rr < 5) ? 11 + rr : 22 + rr;
        s16x8 z = (s16x8)(short)0;
        *(s16x8*)(&sXb[row][c8 * 8]) = z;
    }
    __syncthreads();

    for (int i = tid; i < 22 * 32; i += 256) {
        int row = i >> 5, seg = i & 31;
        *(float4*)(&sX[row][seg * 4]) =
            *(const float4*)(x + (size_t)sNode[row] * DC + seg * 4);
    }
    for (int i = tid; i < 320; i += 256) {
        int row20 = i >> 4, seg = i & 15;
        int bb = row20 / 10, s = row20 - bb * 10;
        *(s16x8*)(&sXb[bb * 16 + s][128 + seg * 8]) =
            *(const s16x8*)(aggF + ((size_t)(b0 + bb) * 10 + s) * 128 + seg * 8);
    }
    __syncthreads();

    {
        int gg = tid >> 5, ln = tid & 31;
        for (int rd = 0, r = gg; rd < 3; ++rd, r += 8) {
            float p = 0.f;
            if (r < 22) {
                int s = (r < 11) ? r : r - 11;
                const float* av = ws + ((s < 10) ? 128 : 0);
                float4 v = *(const float4*)(&sX[r][ln * 4]);
                float4 a = *(const float4*)(av + ln * 4);
                p = dot4(v, a);
            }
            for (int o = 16; o > 0; o >>= 1) p += __shfl_xor(p, o, 32);
            if (r < 22 && ln == 0) sD[r] = p;
        }
    }
    __syncthreads();

    if (tid < 32) {
        int bb = tid >> 4, j = tid & 15;
        float cc = sD[bb * 11 + 10];
        float v = (j < 10) ? lrelu(cc + sD[bb * 11 + j]) : -3.4e38f;
        float m = v;
        for (int o = 8; o > 0; o >>= 1) m = fmaxf(m, __shfl_xor(m, o, 16));
        float e = (j < 10) ? __expf(v - m) : 0.f;
        float ss = e;
        for (int o = 8; o > 0; o >>= 1) ss += __shfl_xor(ss, o, 16);
        if (j < 10) sBeta0[bb][j] = e / ss;
    }
    __syncthreads();

    {
        int bb = tid >> 7, n = tid & 127;
        float acc = 0.f;
        #pragma unroll
        for (int s = 0; s < 10; ++s) acc += sBeta0[bb][s] * sX[bb * 11 + s][n];
        sXb[bb * 16 + 10][128 + n] = (short)f2bf(acc);
    }
    for (int i = tid; i < 22 * 128; i += 256) {
        int m = i >> 7, k = i & 127;
        int row = (m < 11) ? m : m + 5;
        sXb[row][k] = (short)f2bf(sX[m][k]);
    }
    __syncthreads();

    const unsigned short* bpk = (const unsigned short*)(ws + WS_BPK);
    const int nt0 = 2 * w, nt1 = nt0 + 1;
    f32x4 acc00 = {0.f, 0.f, 0.f, 0.f}, acc01 = {0.f, 0.f, 0.f, 0.f};
    f32x4 acc10 = {0.f, 0.f, 0.f, 0.f}, acc11 = {0.f, 0.f, 0.f, 0.f};
    #pragma unroll
    for (int kb = 0; kb < 8; ++kb) {
        s16x8 a0 = *(const s16x8*)(&sXb[l15][kb * 32 + lg16 * 8]);
        s16x8 a1 = *(const s16x8*)(&sXb[16 + l15][kb * 32 + lg16 * 8]);
        s16x8 bw0 = *(const s16x8*)(bpk + ((size_t)(nt0 * 8 + kb) * 64 + lane) * 8);
        s16x8 bw1 = *(const s16x8*)(bpk + ((size_t)(nt1 * 8 + kb) * 64 + lane) * 8);
        acc00 = __builtin_amdgcn_mfma_f32_16x16x32_bf16(a0, bw0, acc00, 0, 0, 0);
        acc01 = __builtin_amdgcn_mfma_f32_16x16x32_bf16(a0, bw1, acc01, 0, 0, 0);
        acc10 = __builtin_amdgcn_mfma_f32_16x16x32_bf16(a1, bw0, acc10, 0, 0, 0);
        acc11 = __builtin_amdgcn_mfma_f32_16x16x32_bf16(a1, bw1, acc11, 0, 0, 0);
    }

    float h00[4], h01[4], h10[4], h11[4];
    #pragma unroll
    for (int r = 0; r < 4; ++r) {
        h00[r] = sigm(acc00[r]); h01[r] = sigm(acc01[r]);
        h10[r] = sigm(acc10[r]); h11[r] = sigm(acc11[r]);
    }

    const int c0 = nt0 * 16 + l15, c1 = nt1 * 16 + l15;
    const float b1c0 = ws[256 + c0], b1c1 = ws[256 + c1];
    const float b2c0 = ws[384 + c0], b2c1 = ws[384 + c1];
    #pragma unroll
    for (int mt = 0; mt < 2; ++mt) {
        #pragma unroll
        for (int r = 0; r < 4; ++r) {
            int s = lg16 * 4 + r;
            float ha = mt ? h10[r] : h00[r];
            float hb = mt ? h11[r] : h01[r];
            float p;
            if (s < 10)       p = ha * b2c0 + hb * b2c1;
            else if (s == 10) p = ha * b1c0 + hb * b1c1;
            else              p = 0.f;
            #pragma unroll
            for (int o = 1; o < 16; o <<= 1) p += __shfl_xor(p, o, 64);
            if (l15 == 0) sLgP[w][mt * 16 + s] = p;
        }
    }
    __syncthreads();

    if (tid < 32) {
        int bb = tid >> 4, j = tid & 15;
        float lgj = 0.f, lg10 = 0.f;
        #pragma unroll
        for (int wv = 0; wv < 4; ++wv) {
            lgj  += sLgP[wv][bb * 16 + j];
            lg10 += sLgP[wv][bb * 16 + 10];
        }
        float v = (j < 10) ? lrelu(lg10 + lgj) : -3.4e38f;
        float m = v;
        for (int o = 8; o > 0; o >>= 1) m = fmaxf(m, __shfl_xor(m, o, 16));
        float e = (j < 10) ? __expf(v - m) : 0.f;
        float ss = e;
        for (int o = 8; o > 0; o >>= 1) ss += __shfl_xor(ss, o, 16);
        if (j < 10) {
            float bh = e / ss;
            sBH[bb][j] = bh;
            out[FEA_SZ + (size_t)(b0 + bb) * 260 + j * 26] = bh;
        }
    }
    __syncthreads();

    #pragma unroll
    for (int bb = 0; bb < 2; ++bb) {
        float p0 = 0.f, p1 = 0.f;
        #pragma unroll
        for (int r = 0; r < 4; ++r) {
            int s = lg16 * 4 + r;
            if (s < 10) {
                float bh = sBH[bb][s];
                p0 += bh * (bb ? h10[r] : h00[r]);
                p1 += bh * (bb ? h11[r] : h01[r]);
            }
        }
        p0 += __shfl_xor(p0, 16, 64); p0 += __shfl_xor(p0, 32, 64);
        p1 += __shfl_xor(p1, 16, 64); p1 += __shfl_xor(p1, 32, 64);
        if (lg16 == 0) {
            sHopH[bb][nt0 * 16 + l15] = p0;
            sHopH[bb][nt1 * 16 + l15] = p1;
        }
    }
    __syncthreads();

    {
        const float* v0t = ws + WS_V0T;
        int c = tid & 127, bb = tid >> 7;
        float acc2 = 0.f;
        for (int dd = 0; dd < 128; dd += 4) {
            float4 hh = *(const float4*)(&sHopH[bb][dd]);
            acc2 += hh.x * v0t[(size_t)(dd + 0) * 128 + c]
                  + hh.y * v0t[(size_t)(dd + 1) * 128 + c]
                  + hh.z * v0t[(size_t)(dd + 2) * 128 + c]
                  + hh.w * v0t[(size_t)(dd + 3) * 128 + c];
        }
        out[(size_t)c * 2048 + b0 + bb] = acc2;
    }
}

extern "C" void kernel_launch(void* const* d_in, const int* in_sizes, int n_in,
                              void* d_out, int out_size, void* d_ws, size_t ws_size,
                              hipStream_t stream) {
    const float* x      = (const float*)d_in[0];
    const int*   samples= (const int*)d_in[1];
    const float* V1h1a  = (const float*)d_in[2];
    const float* w1h1   = (const float*)d_in[3];
    const float* V1h0a  = (const float*)d_in[4];
    const float* w1h0   = (const float*)d_in[5];
    const float* V1h1   = (const float*)d_in[6];
    const float* V1h0   = (const float*)d_in[7];
    const float* Whops  = (const float*)d_in[8];
    float* outp = (float*)d_out;
    float* ws   = (float*)d_ws;
    unsigned short* aggF = (unsigned short*)(ws + WS_AGGF);
    unsigned short* xb   = (unsigned short*)(ws + WS_XB);

    const bool use_bf16x = ws_size >= (size_t)WS_END * sizeof(float);

    if (use_bf16x) {
        hipLaunchKernelGGL(prep_all_kernel, dim3(193 + 2048), dim3(256), 0, stream,
                           V1h1a, w1h1, V1h0a, w1h0, V1h1, Whops, V1h0, x, xb, ws);
        hipLaunchKernelGGL(fused_b_kernel, dim3(2048), dim3(256), 0, stream,
                           xb, samples, ws, outp);
    } else {
        hipLaunchKernelGGL(prep_all_kernel, dim3(193), dim3(256), 0, stream,
                           V1h1a, w1h1, V1h0a, w1h0, V1h1, Whops, V1h0, x, (unsigned short*)nullptr, ws);
        hipLaunchKernelGGL(nbr_kernel, dim3(10, 2048), dim3(256), 0, stream,
                           x, samples, ws, aggF, outp);
        hipLaunchKernelGGL(hopfused_kernel, dim3(1024), dim3(256), 0, stream,
                           x, samples, ws, aggF, outp);
    }
}

// Round 20
// 61.335 us; speedup vs baseline: 1.9795x; 1.9795x over previous
//
#include <hip/hip_runtime.h>
#include <math.h>

#define S1C 10
#define S2C 25
#define DC 128
#define NSAMP 261
#define NBATCH 2048
#define N_NODES 100000
#define FEA_SZ (128*2048)

// ws layout (float slots):
//   [0:128)    a1 = V1h1a^T w1[:128]
//   [128:256)  a2 = V1h1a^T w1[128:]
//   [256:384)  b1 = V1h0a^T w0[:128]
//   [384:512)  b2 = V1h0a^T w0[128:]
//   WS_BPK:  Bpack bf16 (32768 ushorts), MFMA B fragments
//   WS_V0T:  V0t[dd][l] = V1h0[l][dd]  (f32)
//   WS_AGGF: aggF[b][s][128] bf16   [f32 fallback path only]
//   WS_XB:   xb[node][128] bf16     [bf16 path only]
#define WS_BPK   512
#define WS_V0T   (WS_BPK + 16384)
#define WS_AGGF  (WS_V0T + 16384)
#define WS_XB    (WS_AGGF + 1310720)
#define WS_END   (WS_XB + 6400000)

typedef float f32x4 __attribute__((ext_vector_type(4)));
typedef short s16x8 __attribute__((ext_vector_type(8)));
typedef short s16x4 __attribute__((ext_vector_type(4)));

__device__ __forceinline__ float lrelu(float v) { return v > 0.f ? v : 0.01f * v; }
__device__ __forceinline__ float sigm(float v) { return 1.f / (1.f + __expf(-v)); }
__device__ __forceinline__ float dot4(float4 a, float4 b) {
    return a.x * b.x + a.y * b.y + a.z * b.z + a.w * b.w;
}
__device__ __forceinline__ unsigned short f2bf(float f) {
    unsigned u = __float_as_uint(f);
    unsigned r = (u + 0x7FFFu + ((u >> 16) & 1u)) >> 16;
    return (unsigned short)r;
}
__device__ __forceinline__ float bf2f(unsigned short us) {
    return __uint_as_float(((unsigned)us) << 16);
}

// Merged prep: blk 0 -> a1/a2/b1/b2; blks 1..128 -> Bpack; blks 129..192 -> V0t;
// blks >= 193 (bf16 path only) -> x -> xb bf16 conversion (grid-stride).
__global__ void prep_all_kernel(const float* __restrict__ Vh1a, const float* __restrict__ w1,
                                const float* __restrict__ Vh0a, const float* __restrict__ w0,
                                const float* __restrict__ V1h1, const float* __restrict__ Whops,
                                const float* __restrict__ V1h0, const float* __restrict__ x,
                                unsigned short* __restrict__ xb, float* __restrict__ ws) {
    const int blk = blockIdx.x, tid = threadIdx.x;
    if (blk == 0) {
        for (int o = tid; o < 512; o += 256) {
            int which = o >> 7, n = o & 127;
            const float* V = (which < 2) ? Vh1a : Vh0a;
            const float* w = (which < 2) ? w1 : w0;
            int off = (which & 1) * 128;
            float acc = 0.f;
            for (int l = 0; l < 128; ++l) acc += V[l * 128 + n] * w[off + l];
            ws[o] = acc;
        }
    } else if (blk <= 128) {
        int e = (blk - 1) * 256 + tid;          // 0..32767
        int j  = e & 7;
        int l  = (e >> 3) & 63;
        int kb = (e >> 9) & 7;
        int nt = (e >> 12) & 7;
        int d  = nt * 16 + (l & 15);
        int k  = kb * 32 + ((l >> 4) & 3) * 8 + j;
        int which = k >> 7, kk = k & 127;
        float acc = 0.f;
        for (int jj = 0; jj < 128; ++jj)
            acc += Whops[(size_t)d * 256 + which * 128 + jj] * V1h1[(size_t)jj * 128 + kk];
        unsigned short* bpk = (unsigned short*)(ws + WS_BPK);
        bpk[e] = f2bf(acc);
    } else if (blk <= 192) {
        int dd = (blk - 129) * 2 + (tid >> 7);
        int l = tid & 127;
        ws[WS_V0T + (size_t)dd * 128 + l] = V1h0[(size_t)l * 128 + dd];
    } else {
        const int total4 = N_NODES * DC / 4;    // 3,200,000
        const int stride = (gridDim.x - 193) * 256;
        const float4* x4 = (const float4*)x;
        for (int i = (blk - 193) * 256 + tid; i < total4; i += stride) {
            float4 v = x4[i];
            s16x4 o;
            o[0] = (short)f2bf(v.x); o[1] = (short)f2bf(v.y);
            o[2] = (short)f2bf(v.z); o[3] = (short)f2bf(v.w);
            *(s16x4*)(xb + (size_t)i * 4) = o;
        }
    }
}

// ============================ bf16 fused path ============================

// ONE b per block (grid 2048, 4 waves, (256,4)). PROVEN R14/R18 form: runtime
// s-loop with ONE register row-buffer. Do NOT change: (256,6) squeezes the
// allocator to 40 VGPR + 182 MB spill (R19); unrolling or double-buffering
// the s-loop makes two row-sets live and spills (R15/R17); 8-wave blocks
// lose co-residency (R16).
__global__ __launch_bounds__(256, 4) void fused_b_kernel(
    const unsigned short* __restrict__ xb, const int* __restrict__ samples,
    const float* __restrict__ ws, float* __restrict__ out)
{
    const int b = blockIdx.x;
    const int tid = threadIdx.x;
    const int wv = tid >> 6, l = tid & 63;
    const int g = l >> 4, seg = l & 15;

    __shared__ __align__(16) short sXb[16][264];   // A tile: t1/t0 | agg/tbar
    __shared__ float sDots[4][32];
    __shared__ float sD1[12];                      // d1[s]=t1.a2; [10]=c0=t0.a1
    __shared__ float sBeta0[10];
    __shared__ float sLgP[4][16];
    __shared__ __align__(16) float sHopH[128];
    __shared__ float sBH[16];

    const int* sidx = samples + (size_t)b * NSAMP;

    // zero pad rows 11..15 (both K halves)
    for (int i = tid; i < 165; i += 256) {
        int rr = i / 33, c8 = i - rr * 33;
        *(s16x8*)(&sXb[11 + rr][c8 * 8]) = (s16x8)(short)0;
    }

    // a1/a2 fragments for this lane's 8-elem column slice
    const float* a1p = ws + seg * 8;
    const float* a2p = ws + 128 + seg * 8;
    float a1r[8], a2r[8];
    #pragma unroll
    for (int e = 0; e < 8; ++e) { a1r[e] = a1p[e]; a2r[e] = a2p[e]; }

    // ---- Phase 1: neighbor pairs (runtime loop => single live row-buffer) ----
    for (int s = wv; s < 10; s += 4) {
        s16x8 v0, v1, v2, v3, v4, v5, v6;
        {
            int r;
            r = 0 * 4 + g; v0 = *(const s16x8*)(xb + (size_t)sidx[11 + s * S2C + r] * DC + seg * 8);
            r = 1 * 4 + g; v1 = *(const s16x8*)(xb + (size_t)sidx[11 + s * S2C + r] * DC + seg * 8);
            r = 2 * 4 + g; v2 = *(const s16x8*)(xb + (size_t)sidx[11 + s * S2C + r] * DC + seg * 8);
            r = 3 * 4 + g; v3 = *(const s16x8*)(xb + (size_t)sidx[11 + s * S2C + r] * DC + seg * 8);
            r = 4 * 4 + g; v4 = *(const s16x8*)(xb + (size_t)sidx[11 + s * S2C + r] * DC + seg * 8);
            r = 5 * 4 + g; v5 = *(const s16x8*)(xb + (size_t)sidx[11 + s * S2C + r] * DC + seg * 8);
            r = 6 * 4 + g;  // 24 (g=0), 25=t1 (g=1), idle (g>=2)
            int node = (r == 24) ? sidx[11 + s * S2C + 24] : ((r == 25) ? sidx[1 + s] : sidx[0]);
            v6 = *(const s16x8*)(xb + (size_t)node * DC + seg * 8);
            if (r > 25) v6 = (s16x8)(short)0;
        }

        // dots: neighbors vs a2; t1 row vs a1 (c1) AND a2 (d1[s])
#define ROWDOT(VV, T)                                                            \
        {                                                                        \
            int r = (T) * 4 + g;                                                 \
            float p = 0.f;                                                       \
            _Pragma("unroll")                                                    \
            for (int e = 0; e < 8; ++e)                                          \
                p += bf2f((unsigned short)(VV)[e]) * ((r == 25) ? a1r[e] : a2r[e]); \
            _Pragma("unroll")                                                    \
            for (int o = 8; o > 0; o >>= 1) p += __shfl_xor(p, o, 16);           \
            if (seg == 0 && r <= 25) sDots[wv][r] = p;                           \
        }
        ROWDOT(v0, 0) ROWDOT(v1, 1) ROWDOT(v2, 2) ROWDOT(v3, 3)
        ROWDOT(v4, 4) ROWDOT(v5, 5) ROWDOT(v6, 6)
#undef ROWDOT
        // t1 . a2 (only g==1 holds the t1 row)
        {
            float q = 0.f;
            #pragma unroll
            for (int e = 0; e < 8; ++e) q += bf2f((unsigned short)v6[e]) * a2r[e];
            #pragma unroll
            for (int o = 8; o > 0; o >>= 1) q += __shfl_xor(q, o, 16);
            if (g == 1 && seg == 0) sD1[s] = q;
        }
        asm volatile("" ::: "memory");

        // softmax over 25 (replicated per 32-lane half)
        const int j = l & 31;
        float bt;
        {
            float c1 = sDots[wv][25];
            float dj = (j < 25) ? sDots[wv][j] : 0.f;
            float val = (j < 25) ? lrelu(c1 + dj) : -3.4e38f;
            float m = val;
            #pragma unroll
            for (int o = 16; o > 0; o >>= 1) m = fmaxf(m, __shfl_xor(m, o, 32));
            float e = (j < 25) ? __expf(val - m) : 0.f;
            float ssum = e;
            #pragma unroll
            for (int o = 16; o > 0; o >>= 1) ssum += __shfl_xor(ssum, o, 32);
            bt = e / ssum;
        }
        if (l < 25) out[FEA_SZ + (size_t)b * 260 + s * 26 + 1 + l] = bt;

        // weighted aggregation
        float acc[8];
        #pragma unroll
        for (int e = 0; e < 8; ++e) acc[e] = 0.f;
#define ROWACC(VV, T)                                                            \
        {                                                                        \
            int r = (T) * 4 + g;                                                 \
            float btr = __shfl(bt, r & 31, 32);                                  \
            _Pragma("unroll")                                                    \
            for (int e = 0; e < 8; ++e) acc[e] += btr * bf2f((unsigned short)(VV)[e]); \
        }
        ROWACC(v0, 0) ROWACC(v1, 1) ROWACC(v2, 2) ROWACC(v3, 3)
        ROWACC(v4, 4) ROWACC(v5, 5) ROWACC(v6, 6)
#undef ROWACC
        #pragma unroll
        for (int e = 0; e < 8; ++e) {
            acc[e] += __shfl_xor(acc[e], 16, 64);
            acc[e] += __shfl_xor(acc[e], 32, 64);
        }
        if (g == 0) {
            s16x8 o8;
            #pragma unroll
            for (int e = 0; e < 8; ++e) o8[e] = (short)f2bf(acc[e]);
            *(s16x8*)(&sXb[s][128 + seg * 8]) = o8;
        }
        if (g == 1) *(s16x8*)(&sXb[s][seg * 8]) = v6;   // t1 row into A tile
    }

    // wave 3: t0 row -> sXb[10][0:128), c0 = t0.a1 -> sD1[10]
    if (wv == 3 && g == 0) {
        s16x8 v = *(const s16x8*)(xb + (size_t)sidx[0] * DC + seg * 8);
        *(s16x8*)(&sXb[10][seg * 8]) = v;
        float p = 0.f;
        #pragma unroll
        for (int e = 0; e < 8; ++e) p += bf2f((unsigned short)v[e]) * a1r[e];
        #pragma unroll
        for (int o = 8; o > 0; o >>= 1) p += __shfl_xor(p, o, 16);
        if (seg == 0) sD1[10] = p;
    }
    __syncthreads();

    // ---- beta0 ----
    if (tid < 16) {
        float cc = sD1[10];
        float v = (tid < 10) ? lrelu(cc + sD1[tid]) : -3.4e38f;
        float m = v;
        for (int o = 8; o > 0; o >>= 1) m = fmaxf(m, __shfl_xor(m, o, 16));
        float e = (tid < 10) ? __expf(v - m) : 0.f;
        float ss = e;
        for (int o = 8; o > 0; o >>= 1) ss += __shfl_xor(ss, o, 16);
        if (tid < 10) sBeta0[tid] = e / ss;
    }
    __syncthreads();

    // tbar -> agg half of row 10
    if (tid < 128) {
        float acc = 0.f;
        #pragma unroll
        for (int s = 0; s < 10; ++s)
            acc += sBeta0[s] * bf2f((unsigned short)sXb[s][tid]);
        sXb[10][128 + tid] = (short)f2bf(acc);
    }
    __syncthreads();

    // ---- MFMA GEMM: wave wv covers n-tiles {2wv, 2wv+1}, 8 k-blocks ----
    const unsigned short* bpk = (const unsigned short*)(ws + WS_BPK);
    const int lane = l;
    const int lg16 = l >> 4, l15 = l & 15;
    const int nt0 = 2 * wv, nt1 = nt0 + 1;
    f32x4 acc0 = {0.f, 0.f, 0.f, 0.f}, acc1 = {0.f, 0.f, 0.f, 0.f};
    #pragma unroll
    for (int kb = 0; kb < 8; ++kb) {
        s16x8 a0 = *(const s16x8*)(&sXb[l15][kb * 32 + lg16 * 8]);
        s16x8 bw0 = *(const s16x8*)(bpk + ((size_t)(nt0 * 8 + kb) * 64 + lane) * 8);
        s16x8 bw1 = *(const s16x8*)(bpk + ((size_t)(nt1 * 8 + kb) * 64 + lane) * 8);
        acc0 = __builtin_amdgcn_mfma_f32_16x16x32_bf16(a0, bw0, acc0, 0, 0, 0);
        acc1 = __builtin_amdgcn_mfma_f32_16x16x32_bf16(a0, bw1, acc1, 0, 0, 0);
    }

    float h0[4], h1[4];
    #pragma unroll
    for (int r = 0; r < 4; ++r) { h0[r] = sigm(acc0[r]); h1[r] = sigm(acc1[r]); }

    // logit partials over this wave's 32 cols
    const int c0 = nt0 * 16 + l15, c1 = nt1 * 16 + l15;
    const float b1c0 = ws[256 + c0], b1c1 = ws[256 + c1];
    const float b2c0 = ws[384 + c0], b2c1 = ws[384 + c1];
    #pragma unroll
    for (int r = 0; r < 4; ++r) {
        int s = lg16 * 4 + r;
        float p;
        if (s < 10)       p = h0[r] * b2c0 + h1[r] * b2c1;
        else if (s == 10) p = h0[r] * b1c0 + h1[r] * b1c1;
        else              p = 0.f;
        #pragma unroll
        for (int o = 1; o < 16; o <<= 1) p += __shfl_xor(p, o, 64);
        if (l15 == 0) sLgP[wv][s] = p;
    }
    __syncthreads();

    // beta_h
    if (tid < 16) {
        float lgj = 0.f, lg10 = 0.f;
        #pragma unroll
        for (int w2 = 0; w2 < 4; ++w2) {
            lgj  += sLgP[w2][tid];
            lg10 += sLgP[w2][10];
        }
        float v = (tid < 10) ? lrelu(lg10 + lgj) : -3.4e38f;
        float m = v;
        for (int o = 8; o > 0; o >>= 1) m = fmaxf(m, __shfl_xor(m, o, 16));
        float e = (tid < 10) ? __expf(v - m) : 0.f;
        float ss = e;
        for (int o = 8; o > 0; o >>= 1) ss += __shfl_xor(ss, o, 16);
        float bh = (tid < 10) ? e / ss : 0.f;
        sBH[tid] = bh;
        if (tid < 10) out[FEA_SZ + (size_t)b * 260 + tid * 26] = bh;
    }
    __syncthreads();

    // hopH[c] = sum_s bh[s] h[s][c]
    {
        float p0 = 0.f, p1 = 0.f;
        #pragma unroll
        for (int r = 0; r < 4; ++r) {
            int s = lg16 * 4 + r;
            float bh = sBH[s];
            p0 += bh * h0[r];
            p1 += bh * h1[r];
        }
        p0 += __shfl_xor(p0, 16, 64); p0 += __shfl_xor(p0, 32, 64);
        p1 += __shfl_xor(p1, 16, 64); p1 += __shfl_xor(p1, 32, 64);
        if (lg16 == 0) {
            sHopH[c0] = p0;
            sHopH[c1] = p1;
        }
    }
    __syncthreads();

    // projection: fea_out[c] = sum_dd hopH[dd] V0t[dd][c]; out is fea_out^T
    if (tid < 128) {
        const float* v0t = ws + WS_V0T;
        float acc2 = 0.f;
        for (int dd = 0; dd < 128; dd += 4) {
            float4 hh = *(const float4*)(&sHopH[dd]);
            acc2 += hh.x * v0t[(size_t)(dd + 0) * 128 + tid]
                  + hh.y * v0t[(size_t)(dd + 1) * 128 + tid]
                  + hh.z * v0t[(size_t)(dd + 2) * 128 + tid]
                  + hh.w * v0t[(size_t)(dd + 3) * 128 + tid];
        }
        out[(size_t)tid * 2048 + b] = acc2;
    }
}

// ============================ f32 fallback path (R8, proven) ============================

__global__ __launch_bounds__(256) void nbr_kernel(
    const float* __restrict__ x, const int* __restrict__ samples,
    const float* __restrict__ ws, unsigned short* __restrict__ aggF,
    float* __restrict__ out)
{
    const int s = blockIdx.x, b = blockIdx.y;
    const int tid = threadIdx.x, g = tid >> 5, lane = tid & 31;

    __shared__ __align__(16) float sNbr[25][132];
    __shared__ float sD[26];
    __shared__ float sBeta[25];

    float4 a1v = *(const float4*)(ws + lane * 4);
    float4 a2v = *(const float4*)(ws + 128 + lane * 4);
    const int* sidx = samples + (size_t)b * NSAMP;

    const bool has3 = (g < 2);
    int n0 = sidx[11 + s * S2C + g];
    int n1 = sidx[11 + s * S2C + 8 + g];
    int n2 = sidx[11 + s * S2C + 16 + g];
    int n3 = has3 ? ((g == 0) ? sidx[11 + s * S2C + 24] : sidx[1 + s]) : 0;

    float4 v0 = *(const float4*)(x + (size_t)n0 * DC + lane * 4);
    float4 v1 = *(const float4*)(x + (size_t)n1 * DC + lane * 4);
    float4 v2 = *(const float4*)(x + (size_t)n2 * DC + lane * 4);
    float4 v3 = make_float4(0.f, 0.f, 0.f, 0.f);
    if (has3) v3 = *(const float4*)(x + (size_t)n3 * DC + lane * 4);

    *(float4*)(&sNbr[g][lane * 4]) = v0;
    *(float4*)(&sNbr[8 + g][lane * 4]) = v1;
    *(float4*)(&sNbr[16 + g][lane * 4]) = v2;
    if (g == 0) *(float4*)(&sNbr[24][lane * 4]) = v3;

    float p0 = dot4(v0, a2v);
    float p1 = dot4(v1, a2v);
    float p2 = dot4(v2, a2v);
    float p3 = has3 ? dot4(v3, (g == 0) ? a2v : a1v) : 0.f;
    #pragma unroll
    for (int o = 16; o > 0; o >>= 1) {
        p0 += __shfl_xor(p0, o, 32);
        p1 += __shfl_xor(p1, o, 32);
        p2 += __shfl_xor(p2, o, 32);
        p3 += __shfl_xor(p3, o, 32);
    }
    if (lane == 0) {
        sD[g] = p0; sD[8 + g] = p1; sD[16 + g] = p2;
        if (has3) sD[24 + g] = p3;
    }
    __syncthreads();

    if (tid < 32) {
        float c1 = sD[25];
        float v = (lane < 25) ? lrelu(c1 + sD[lane]) : -3.4e38f;
        float m = v;
        for (int o = 16; o > 0; o >>= 1) m = fmaxf(m, __shfl_xor(m, o, 32));
        float e = (lane < 25) ? __expf(v - m) : 0.f;
        float ssum = e;
        for (int o = 16; o > 0; o >>= 1) ssum += __shfl_xor(ssum, o, 32);
        if (lane < 25) {
            float bt = e / ssum;
            sBeta[lane] = bt;
            out[FEA_SZ + (size_t)b * 260 + s * 26 + 1 + lane] = bt;
        }
    }
    __syncthreads();

    if (tid < 128) {
        float acc = 0.f;
        #pragma unroll
        for (int t = 0; t < 25; ++t) acc += sBeta[t] * sNbr[t][tid];
        aggF[((size_t)b * 10 + s) * 128 + tid] = f2bf(acc);
    }
}

__global__ __launch_bounds__(256, 4) void hopfused_kernel(
    const float* __restrict__ x, const int* __restrict__ samples,
    const float* __restrict__ ws, const unsigned short* __restrict__ aggF,
    float* __restrict__ out)
{
    const int b0 = blockIdx.x * 2;
    const int tid = threadIdx.x;
    const int w = tid >> 6;
    const int lane = tid & 63;
    const int lg16 = lane >> 4;
    const int l15 = lane & 15;

    __shared__ __align__(16) float sX[22][128];
    __shared__ __align__(16) short sXb[32][264];
    __shared__ float sLgP[4][32];
    __shared__ __align__(16) float sHopH[2][128];
    __shared__ float sD[22];
    __shared__ float sBeta0[2][10];
    __shared__ float sBH[2][10];
    __shared__ int sNode[22];

    if (tid < 22) {
        int bb = tid / 11, s = tid - bb * 11;
        sNode[tid] = (s < 10) ? samples[(size_t)(b0 + bb) * NSAMP + 1 + s]
                              : samples[(size_t)(b0 + bb) * NSAMP];
    }
    for (int i = tid; i < 330; i += 256) {
        int rr = i / 33, c8 = i - rr * 33;
        int row = (rr < 5) ? 11 + rr : 22 + rr;
        s16x8 z = (s16x8)(short)0;
        *(s16x8*)(&sXb[row][c8 * 8]) = z;
    }
    __syncthreads();

    for (int i = tid; i < 22 * 32; i += 256) {
        int row = i >> 5, seg = i & 31;
        *(float4*)(&sX[row][seg * 4]) =
            *(const float4*)(x + (size_t)sNode[row] * DC + seg * 4);
    }
    for (int i = tid; i < 320; i += 256) {
        int row20 = i >> 4, seg = i & 15;
        int bb = row20 / 10, s = row20 - bb * 10;
        *(s16x8*)(&sXb[bb * 16 + s][128 + seg * 8]) =
            *(const s16x8*)(aggF + ((size_t)(b0 + bb) * 10 + s) * 128 + seg * 8);
    }
    __syncthreads();

    {
        int gg = tid >> 5, ln = tid & 31;
        for (int rd = 0, r = gg; rd < 3; ++rd, r += 8) {
            float p = 0.f;
            if (r < 22) {
                int s = (r < 11) ? r : r - 11;
                const float* av = ws + ((s < 10) ? 128 : 0);
                float4 v = *(const float4*)(&sX[r][ln * 4]);
                float4 a = *(const float4*)(av + ln * 4);
                p = dot4(v, a);
            }
            for (int o = 16; o > 0; o >>= 1) p += __shfl_xor(p, o, 32);
            if (r < 22 && ln == 0) sD[r] = p;
        }
    }
    __syncthreads();

    if (tid < 32) {
        int bb = tid >> 4, j = tid & 15;
        float cc = sD[bb * 11 + 10];
        float v = (j < 10) ? lrelu(cc + sD[bb * 11 + j]) : -3.4e38f;
        float m = v;
        for (int o = 8; o > 0; o >>= 1) m = fmaxf(m, __shfl_xor(m, o, 16));
        float e = (j < 10) ? __expf(v - m) : 0.f;
        float ss = e;
        for (int o = 8; o > 0; o >>= 1) ss += __shfl_xor(ss, o, 16);
        if (j < 10) sBeta0[bb][j] = e / ss;
    }
    __syncthreads();

    {
        int bb = tid >> 7, n = tid & 127;
        float acc = 0.f;
        #pragma unroll
        for (int s = 0; s < 10; ++s) acc += sBeta0[bb][s] * sX[bb * 11 + s][n];
        sXb[bb * 16 + 10][128 + n] = (short)f2bf(acc);
    }
    for (int i = tid; i < 22 * 128; i += 256) {
        int m = i >> 7, k = i & 127;
        int row = (m < 11) ? m : m + 5;
        sXb[row][k] = (short)f2bf(sX[m][k]);
    }
    __syncthreads();

    const unsigned short* bpk = (const unsigned short*)(ws + WS_BPK);
    const int nt0 = 2 * w, nt1 = nt0 + 1;
    f32x4 acc00 = {0.f, 0.f, 0.f, 0.f}, acc01 = {0.f, 0.f, 0.f, 0.f};
    f32x4 acc10 = {0.f, 0.f, 0.f, 0.f}, acc11 = {0.f, 0.f, 0.f, 0.f};
    #pragma unroll
    for (int kb = 0; kb < 8; ++kb) {
        s16x8 a0 = *(const s16x8*)(&sXb[l15][kb * 32 + lg16 * 8]);
        s16x8 a1 = *(const s16x8*)(&sXb[16 + l15][kb * 32 + lg16 * 8]);
        s16x8 bw0 = *(const s16x8*)(bpk + ((size_t)(nt0 * 8 + kb) * 64 + lane) * 8);
        s16x8 bw1 = *(const s16x8*)(bpk + ((size_t)(nt1 * 8 + kb) * 64 + lane) * 8);
        acc00 = __builtin_amdgcn_mfma_f32_16x16x32_bf16(a0, bw0, acc00, 0, 0, 0);
        acc01 = __builtin_amdgcn_mfma_f32_16x16x32_bf16(a0, bw1, acc01, 0, 0, 0);
        acc10 = __builtin_amdgcn_mfma_f32_16x16x32_bf16(a1, bw0, acc10, 0, 0, 0);
        acc11 = __builtin_amdgcn_mfma_f32_16x16x32_bf16(a1, bw1, acc11, 0, 0, 0);
    }

    float h00[4], h01[4], h10[4], h11[4];
    #pragma unroll
    for (int r = 0; r < 4; ++r) {
        h00[r] = sigm(acc00[r]); h01[r] = sigm(acc01[r]);
        h10[r] = sigm(acc10[r]); h11[r] = sigm(acc11[r]);
    }

    const int c0 = nt0 * 16 + l15, c1 = nt1 * 16 + l15;
    const float b1c0 = ws[256 + c0], b1c1 = ws[256 + c1];
    const float b2c0 = ws[384 + c0], b2c1 = ws[384 + c1];
    #pragma unroll
    for (int mt = 0; mt < 2; ++mt) {
        #pragma unroll
        for (int r = 0; r < 4; ++r) {
            int s = lg16 * 4 + r;
            float ha = mt ? h10[r] : h00[r];
            float hb = mt ? h11[r] : h01[r];
            float p;
            if (s < 10)       p = ha * b2c0 + hb * b2c1;
            else if (s == 10) p = ha * b1c0 + hb * b1c1;
            else              p = 0.f;
            #pragma unroll
            for (int o = 1; o < 16; o <<= 1) p += __shfl_xor(p, o, 64);
            if (l15 == 0) sLgP[w][mt * 16 + s] = p;
        }
    }
    __syncthreads();

    if (tid < 32) {
        int bb = tid >> 4, j = tid & 15;
        float lgj = 0.f, lg10 = 0.f;
        #pragma unroll
        for (int wv = 0; wv < 4; ++wv) {
            lgj  += sLgP[wv][bb * 16 + j];
            lg10 += sLgP[wv][bb * 16 + 10];
        }
        float v = (j < 10) ? lrelu(lg10 + lgj) : -3.4e38f;
        float m = v;
        for (int o = 8; o > 0; o >>= 1) m = fmaxf(m, __shfl_xor(m, o, 16));
        float e = (j < 10) ? __expf(v - m) : 0.f;
        float ss = e;
        for (int o = 8; o > 0; o >>= 1) ss += __shfl_xor(ss, o, 16);
        if (j < 10) {
            float bh = e / ss;
            sBH[bb][j] = bh;
            out[FEA_SZ + (size_t)(b0 + bb) * 260 + j * 26] = bh;
        }
    }
    __syncthreads();

    #pragma unroll
    for (int bb = 0; bb < 2; ++bb) {
        float p0 = 0.f, p1 = 0.f;
        #pragma unroll
        for (int r = 0; r < 4; ++r) {
            int s = lg16 * 4 + r;
            if (s < 10) {
                float bh = sBH[bb][s];
                p0 += bh * (bb ? h10[r] : h00[r]);
                p1 += bh * (bb ? h11[r] : h01[r]);
            }
        }
        p0 += __shfl_xor(p0, 16, 64); p0 += __shfl_xor(p0, 32, 64);
        p1 += __shfl_xor(p1, 16, 64); p1 += __shfl_xor(p1, 32, 64);
        if (lg16 == 0) {
            sHopH[bb][nt0 * 16 + l15] = p0;
            sHopH[bb][nt1 * 16 + l15] = p1;
        }
    }
    __syncthreads();

    {
        const float* v0t = ws + WS_V0T;
        int c = tid & 127, bb = tid >> 7;
        float acc2 = 0.f;
        for (int dd = 0; dd < 128; dd += 4) {
            float4 hh = *(const float4*)(&sHopH[bb][dd]);
            acc2 += hh.x * v0t[(size_t)(dd + 0) * 128 + c]
                  + hh.y * v0t[(size_t)(dd + 1) * 128 + c]
                  + hh.z * v0t[(size_t)(dd + 2) * 128 + c]
                  + hh.w * v0t[(size_t)(dd + 3) * 128 + c];
        }
        out[(size_t)c * 2048 + b0 + bb] = acc2;
    }
}

extern "C" void kernel_launch(void* const* d_in, const int* in_sizes, int n_in,
                              void* d_out, int out_size, void* d_ws, size_t ws_size,
                              hipStream_t stream) {
    const float* x      = (const float*)d_in[0];
    const int*   samples= (const int*)d_in[1];
    const float* V1h1a  = (const float*)d_in[2];
    const float* w1h1   = (const float*)d_in[3];
    const float* V1h0a  = (const float*)d_in[4];
    const float* w1h0   = (const float*)d_in[5];
    const float* V1h1   = (const float*)d_in[6];
    const float* V1h0   = (const float*)d_in[7];
    const float* Whops  = (const float*)d_in[8];
    float* outp = (float*)d_out;
    float* ws   = (float*)d_ws;
    unsigned short* aggF = (unsigned short*)(ws + WS_AGGF);
    unsigned short* xb   = (unsigned short*)(ws + WS_XB);

    const bool use_bf16x = ws_size >= (size_t)WS_END * sizeof(float);

    if (use_bf16x) {
        hipLaunchKernelGGL(prep_all_kernel, dim3(193 + 2048), dim3(256), 0, stream,
                           V1h1a, w1h1, V1h0a, w1h0, V1h1, Whops, V1h0, x, xb, ws);
        hipLaunchKernelGGL(fused_b_kernel, dim3(2048), dim3(256), 0, stream,
                           xb, samples, ws, outp);
    } else {
        hipLaunchKernelGGL(prep_all_kernel, dim3(193), dim3(256), 0, stream,
                           V1h1a, w1h1, V1h0a, w1h0, V1h1, Whops, V1h0, x, (unsigned short*)nullptr, ws);
        hipLaunchKernelGGL(nbr_kernel, dim3(10, 2048), dim3(256), 0, stream,
                           x, samples, ws, aggF, outp);
        hipLaunchKernelGGL(hopfused_kernel, dim3(1024), dim3(256), 0, stream,
                           x, samples, ws, aggF, outp);
    }
}